// Round 7
// baseline (217.082 us; speedup 1.0000x reference)
//
#include <hip/hip_runtime.h>
#include <stdint.h>

#define HWP 784                // 28*28
#define NPOS 50176             // 64*784 flat positions
#define PLN ((size_t)NPOS * 64)  // plane stride bytes: [g][pos][64ch]
#define PAD_OFF 47616          // slab offset of the 256-B pad row (186*256)

typedef int   int4v   __attribute__((ext_vector_type(4)));
typedef int   int16v  __attribute__((ext_vector_type(16)));
typedef float float4v __attribute__((ext_vector_type(4)));
using as1_cv = const __attribute__((address_space(1))) void;
using as3_v  = __attribute__((address_space(3))) void;

// ---------------- kernel 1: x NCHW fp32 -> plane-blocked i8 (value-128) -------------
__global__ __launch_bounds__(256) void k_nhwc(const float* __restrict__ x,
                                              int8_t* __restrict__ x8) {
    __shared__ int lA[256 * 15];                 // [c][pq] pos-packed, stride 15
    __shared__ __align__(16) int lB[56 * 68];    // [pos][ch-dword 0..63], stride 68
    const int tid = threadIdx.x;
    const int P0 = blockIdx.x * 56;
    const int n = P0 / HWP;
    const int hw0 = P0 % HWP;
    const float* xb = x + (size_t)n * 256 * HWP + hw0;
#pragma unroll
    for (int k = 0; k < 14; ++k) {               // 3584 float4 chunks
        int e = tid + k * 256;
        int c = e / 14, pq = e % 14;
        float4v v = *(const float4v*)(xb + (size_t)c * HWP + pq * 4);
        int b0 = ((int)v[0] - 128) & 255;
        int b1 = ((int)v[1] - 128) & 255;
        int b2 = ((int)v[2] - 128) & 255;
        int b3 = ((int)v[3] - 128) & 255;
        lA[c * 15 + pq] = b0 | (b1 << 8) | (b2 << 16) | (b3 << 24);
    }
    __syncthreads();
#pragma unroll
    for (int k = 0; k < 4; ++k) {                // 896 4x4 byte-transpose units
        int u = tid + k * 256;
        if (u < 896) {
            int cg = u / 14, pq = u % 14;
            int d0 = lA[(cg * 4 + 0) * 15 + pq];
            int d1 = lA[(cg * 4 + 1) * 15 + pq];
            int d2 = lA[(cg * 4 + 2) * 15 + pq];
            int d3 = lA[(cg * 4 + 3) * 15 + pq];
#pragma unroll
            for (int j = 0; j < 4; ++j) {
                int sh = j * 8;
                int o = ((d0 >> sh) & 255) | (((d1 >> sh) & 255) << 8)
                      | (((d2 >> sh) & 255) << 16) | (((d3 >> sh) & 255) << 24);
                lB[(pq * 4 + j) * 68 + cg] = o;
            }
        }
    }
    __syncthreads();
#pragma unroll
    for (int k = 0; k < 4; ++k) {                // 896 16B output chunks
        int ch = tid + k * 256;
        if (ch < 896) {
            int g = ch / 224, rem = ch % 224;
            int pos = rem >> 2, c4 = rem & 3;
            int4v val = *(const int4v*)&lB[pos * 68 + g * 16 + c4 * 4];
            *(int4v*)(x8 + (size_t)g * PLN + (size_t)(P0 + pos) * 64 + c4 * 16) = val;
        }
    }
}

// ---------------- kernel 2: weights OIHW fp32 -> fragment-major int8 + per-oc sums --
// byte index: ((((tap*4+kb)*2+s)*8 + gg)*64 + l)*16 + j
//   oc = gg*32 + (l&31); ic = kb*64 + s*32 + (l>>5)*16 + j
__global__ __launch_bounds__(256) void k_w_prep(const float* __restrict__ w,
                                                int8_t* __restrict__ w8,
                                                int* __restrict__ wsum) {
    __shared__ int red[256];
    const int oc = blockIdx.x;
    const int t = threadIdx.x;          // t = ic
    const float* src = w + (size_t)oc * 2304 + (size_t)t * 9;
    const int g = oc >> 5;
    const int l = ((t >> 4) & 1) * 32 + (oc & 31);
    const int j = t & 15;
    const int s2 = (t >> 5) & 1;
    const int kb = t >> 6;
    int acc = 0;
#pragma unroll
    for (int tap = 0; tap < 9; ++tap) {
        int wv = (int)src[tap];
        acc += wv;
        int oo = ((((tap * 4 + kb) * 2 + s2) * 8 + g) * 64 + l) * 16 + j;
        w8[oo] = (int8_t)wv;
    }
    red[t] = acc;
    __syncthreads();
    for (int st = 128; st > 0; st >>= 1) {
        if (t < st) red[t] += red[t + st];
        __syncthreads();
    }
    if (t == 0) wsum[oc] = red[0];
}

// ---------------- kernel 3: quantized 3x3 conv, 128pos x 128oc blocks ---------------
// Wave = 64 pos (mt=2) x 64 oc (nt=2): 16 MFMAs (586 SIMD-cyc) per K-step so one
// step's issue shadow exceeds every load latency.  A-slab (186 rows + pad row) staged
// once via global_load_lds (XOR-16 swizzle); A and B fragments prefetched one full
// step ahead; fully unrolled 36-step loop; MFMAs interleaved across the 4 accs.
// Out-of-image taps read a pad row (z_in-128 splat) selected by ONE cndmask per
// (tap,mt); epilogue adds (128-z_in)*Wsum[oc] -> exact integer arithmetic.
template<bool FUSED>
__global__ __launch_bounds__(256, 3) void k_qconv_t(const int8_t* __restrict__ in8,
        const int8_t* __restrict__ w8, const int* __restrict__ wsum,
        const float* __restrict__ s_in_p, const float* __restrict__ s_w_p,
        const float* __restrict__ s_out_p, const float* __restrict__ z_in_p,
        const float* __restrict__ z_out_p, int8_t* __restrict__ out8,
        const int8_t* __restrict__ x8, const float* __restrict__ sxp,
        const float* __restrict__ zxp, const float* __restrict__ sap,
        const float* __restrict__ zap, float* __restrict__ outf) {
    __shared__ __align__(16) int8_t slab[47872];   // 186 rows x 256 B + pad row
    const int tid = threadIdx.x;
    const int lane = tid & 63;
    const int half = lane >> 5;
    const int wv = tid >> 6;
    const int wq = wv >> 1;            // pos-half of block
    const int wo = wv & 1;             // oc-half of block
    const int p0 = blockIdx.x * 128;   // 392 position tiles
    const int gB = blockIdx.y * 128;   // 2 oc-blocks of 128

    // ---- stage A-slab: 2976 16B chunks; slot (q,cs) holds global chunk cs ^ (q&15)
#pragma unroll
    for (int k = 0; k < 12; ++k) {
        int chunkid = tid + k * 256;
        if (chunkid < 2976) {
            int q = chunkid >> 4;
            int cs = chunkid & 15;
            int cg = cs ^ (q & 15);
            int qg = p0 - 29 + q;
            qg = qg < 0 ? 0 : (qg > NPOS - 1 ? NPOS - 1 : qg);
            const int8_t* src = in8 + (size_t)(cg >> 2) * PLN
                                    + (size_t)qg * 64 + (cg & 3) * 16;
            __builtin_amdgcn_global_load_lds((as1_cv*)src,
                                             (as3_v*)&slab[chunkid * 16], 16, 0, 0);
        }
    }

    // pad row: z_in - 128 splat
    const int zi = (int)z_in_p[0] - 128;
    const int spl = (zi & 0xff) * 0x01010101;
    if (tid < 16) {
        int4v pv; pv[0] = spl; pv[1] = spl; pv[2] = spl; pv[3] = spl;
        *(int4v*)&slab[PAD_OFF + tid * 16] = pv;
    }

    // per-lane geometry + swizzled A base address per (tap, mt)
    int rowpos[2], ph[2], pw[2];
#pragma unroll
    for (int mt = 0; mt < 2; ++mt) {
        rowpos[mt] = wq * 64 + mt * 32 + (lane & 31);
        int p = p0 + rowpos[mt];
        int hw = p % HWP;
        ph[mt] = hw / 28;
        pw[mt] = hw % 28;
    }
    int abz[9][2];
#pragma unroll
    for (int tap = 0; tap < 9; ++tap) {
        const int dh = tap / 3 - 1;
        const int dw = tap % 3 - 1;
#pragma unroll
        for (int mt = 0; mt < 2; ++mt) {
            int q = rowpos[mt] + dh * 28 + dw + 29;          // 0..185
            bool ok = ((unsigned)(ph[mt] + dh) < 28u) & ((unsigned)(pw[mt] + dw) < 28u);
            int base = ok ? (q << 8) : PAD_OFF;              // pad row if out of image
            abz[tap][mt] = base ^ ((q & 15) << 4) ^ (half << 4);
        }
    }

    int16v acc[2][2];
#pragma unroll
    for (int mt = 0; mt < 2; ++mt)
#pragma unroll
        for (int nt = 0; nt < 2; ++nt)
#pragma unroll
            for (int r = 0; r < 16; ++r) acc[mt][nt][r] = 0;

    // B: wave's 64-oc slice; gg0 = oc-group base (32-wide groups)
    const int gg0 = blockIdx.y * 4 + wo * 2;
    const int8_t* wlane = w8 + gg0 * 1024 + lane * 16;

    int4v areg[2][2][2];   // [slot][mt][s]
    int4v breg[2][2][2];   // [slot][nt][s]

#define LOADB(u, slot)                                                      \
    {   const int8_t* wb_ = wlane + (size_t)(u) * 16384;                    \
        breg[slot][0][0] = *(const int4v*)(wb_);                            \
        breg[slot][1][0] = *(const int4v*)(wb_ + 1024);                     \
        breg[slot][0][1] = *(const int4v*)(wb_ + 8192);                     \
        breg[slot][1][1] = *(const int4v*)(wb_ + 9216); }
#define LOADA(u, slot)                                                      \
    {   const int tap_ = (u) >> 2, kb_ = (u) & 3;                           \
        areg[slot][0][0] = *(const int4v*)&slab[abz[tap_][0] ^ ((kb_*4+0)<<4)]; \
        areg[slot][0][1] = *(const int4v*)&slab[abz[tap_][0] ^ ((kb_*4+2)<<4)]; \
        areg[slot][1][0] = *(const int4v*)&slab[abz[tap_][1] ^ ((kb_*4+0)<<4)]; \
        areg[slot][1][1] = *(const int4v*)&slab[abz[tap_][1] ^ ((kb_*4+2)<<4)]; }

    LOADB(0, 0);           // B[0] before the barrier (independent of LDS)

    __syncthreads();       // the only barrier before the K-loop

    LOADA(0, 0);
#pragma unroll
    for (int u = 0; u < 36; ++u) {
        if (u < 35) {      // prefetch next step: one full 586-cyc MFMA shadow of lead
            LOADA(u + 1, (u + 1) & 1);
            LOADB(u + 1, (u + 1) & 1);
        }
        const int sl = u & 1;
#pragma unroll
        for (int s = 0; s < 2; ++s)        // interleave accs: same-acc distance = 4
#pragma unroll
            for (int mt = 0; mt < 2; ++mt)
#pragma unroll
                for (int nt = 0; nt < 2; ++nt)
                    acc[mt][nt] = __builtin_amdgcn_mfma_i32_32x32x32_i8(
                        areg[sl][mt][s], breg[sl][nt][s], acc[mt][nt], 0, 0, 0);
    }
#undef LOADA
#undef LOADB

    // ---- epilogue: requant q = clip(rint(M*acc)+z_out, 0, 255) (exact integer path)
    const float Mf = s_in_p[0] * s_w_p[0] / s_out_p[0];
    const float zof = z_out_p[0];
    const int zoffi = 128 - (int)z_in_p[0];
    const int plane = blockIdx.y * 2 + wo;

    if (!FUSED) {
        int8_t* o8p = out8 + (size_t)plane * PLN;
#pragma unroll
        for (int mt = 0; mt < 2; ++mt)
#pragma unroll
            for (int nt = 0; nt < 2; ++nt) {
                int oc = gB + wo * 64 + nt * 32 + (lane & 31);
                int corr = zoffi * wsum[oc];
#pragma unroll
                for (int r = 0; r < 16; ++r) {
                    int prow = (r & 3) + 8 * (r >> 2) + 4 * half;   // 32x32 C/D layout
                    int pos = p0 + wq * 64 + mt * 32 + prow;
                    float q = rintf(Mf * (float)(acc[mt][nt][r] + corr)) + zof;
                    q = fminf(fmaxf(q, 0.0f), 255.0f);
                    o8p[(size_t)pos * 64 + nt * 32 + (lane & 31)] = (int8_t)((int)q - 128);
                }
            }
    } else {
        // fused residual qadd: out = clip(rint(ra*(qx-zx) + rb*(q2-z2)) + za, 0, 255)
        const float ra = sxp[0] / sap[0];
        const float rb = s_out_p[0] / sap[0];
        const float zx = zxp[0];
        const float z2 = z_out_p[0];
        const float za = zap[0];
        __syncthreads();                        // all waves done with slab A-data
        float* tp = (float*)slab + wv * 2080;   // 32 pos x 64 oc fp32, stride 65
        const int pl = lane & 31;
#pragma unroll
        for (int mt = 0; mt < 2; ++mt) {
#pragma unroll
            for (int nt = 0; nt < 2; ++nt) {
                int oc = gB + wo * 64 + nt * 32 + (lane & 31);
                int corr = zoffi * wsum[oc];
#pragma unroll
                for (int r = 0; r < 16; ++r) {
                    int prow = (r & 3) + 8 * (r >> 2) + 4 * half;
                    float q2 = rintf(Mf * (float)(acc[mt][nt][r] + corr)) + zof;
                    q2 = fminf(fmaxf(q2, 0.0f), 255.0f);
                    tp[prow * 65 + nt * 32 + (lane & 31)] = q2;
                }
            }
            // same-wave readback (DS in-order per wave; next mt overwrite is ordered)
            const int pglob = p0 + wq * 64 + mt * 32 + pl;
            const int n = pglob / HWP;
            const int hwo = pglob % HWP;
            const int8_t* x8p = x8 + (size_t)plane * PLN + (size_t)pglob * 64 + half * 32;
            int4v r0 = *(const int4v*)x8p;
            int4v r1 = *(const int4v*)(x8p + 16);
            int xb[8];
            xb[0] = r0[0]; xb[1] = r0[1]; xb[2] = r0[2]; xb[3] = r0[3];
            xb[4] = r1[0]; xb[5] = r1[1]; xb[6] = r1[2]; xb[7] = r1[3];
            float* obase = outf + ((size_t)(n * 256 + gB + wo * 64 + half * 32)) * HWP + hwo;
#pragma unroll
            for (int j = 0; j < 32; ++j) {
                int bv = (xb[j >> 2] >> ((j & 3) * 8)) & 255;
                int xval = (int)(int8_t)bv + 128;
                float q2 = tp[pl * 65 + half * 32 + j];
                float y = ra * ((float)xval - zx) + rb * (q2 - z2);
                float qf = rintf(y) + za;
                qf = fminf(fmaxf(qf, 0.0f), 255.0f);
                obase[(size_t)j * HWP] = qf;
            }
        }
    }
}

extern "C" void kernel_launch(void* const* d_in, const int* in_sizes, int n_in,
                              void* d_out, int out_size, void* d_ws, size_t ws_size,
                              hipStream_t stream) {
    (void)in_sizes; (void)n_in; (void)out_size; (void)ws_size;
    const float* x    = (const float*)d_in[0];
    const float* w1   = (const float*)d_in[1];
    const float* w2   = (const float*)d_in[2];
    const float* s_x  = (const float*)d_in[3];
    const float* z_x  = (const float*)d_in[4];
    const float* s_w1 = (const float*)d_in[5];
    const float* s_c1 = (const float*)d_in[6];
    const float* z_c1 = (const float*)d_in[7];
    const float* s_w2 = (const float*)d_in[8];
    const float* s_c2 = (const float*)d_in[9];
    const float* z_c2 = (const float*)d_in[10];
    const float* s_ad = (const float*)d_in[11];
    const float* z_ad = (const float*)d_in[12];
    float* out = (float*)d_out;

    // workspace layout (~26.9 MB)
    int8_t* ws    = (int8_t*)d_ws;
    int8_t* x8    = ws;                       // 4 planes x 3,211,264 = 12,845,056
    int8_t* o1    = ws + 12845056;            // 12,845,056 (conv1 out, plane-blocked)
    int8_t* w8a   = ws + 25690112;            // 589,824
    int8_t* w8b   = ws + 26279936;            // 589,824
    int*    wsum1 = (int*)(ws + 26869760);    // 1024
    int*    wsum2 = (int*)(ws + 26870784);    // 1024

    k_nhwc<<<896, 256, 0, stream>>>(x, x8);
    k_w_prep<<<256, 256, 0, stream>>>(w1, w8a, wsum1);
    k_w_prep<<<256, 256, 0, stream>>>(w2, w8b, wsum2);
    k_qconv_t<false><<<dim3(392, 2), 256, 0, stream>>>(x8, w8a, wsum1,
        s_x, s_w1, s_c1, z_x, z_c1, o1,
        nullptr, nullptr, nullptr, nullptr, nullptr, nullptr);
    k_qconv_t<true><<<dim3(392, 2), 256, 0, stream>>>(o1, w8b, wsum2,
        s_c1, s_w2, s_c2, z_c1, z_c2, nullptr,
        x8, s_x, z_x, s_ad, z_ad, out);
}

// Round 8
// 212.834 us; speedup vs baseline: 1.0200x; 1.0200x over previous
//
#include <hip/hip_runtime.h>
#include <stdint.h>

#define HWP 784                // 28*28
#define NPOS 50176             // 64*784 flat positions
#define PLN ((size_t)NPOS * 64)  // plane stride bytes: [g][pos][64ch]
#define PAD_OFF 47616          // slab offset of the 256-B pad row (186*256)

typedef int   int4v   __attribute__((ext_vector_type(4)));
typedef int   int16v  __attribute__((ext_vector_type(16)));
typedef float float4v __attribute__((ext_vector_type(4)));
using as1_cv = const __attribute__((address_space(1))) void;
using as3_v  = __attribute__((address_space(3))) void;

// ---------------- kernel 1: x NCHW fp32 -> plane-blocked i8 (value-128) -------------
__global__ __launch_bounds__(256) void k_nhwc(const float* __restrict__ x,
                                              int8_t* __restrict__ x8) {
    __shared__ int lA[256 * 15];                 // [c][pq] pos-packed, stride 15
    __shared__ __align__(16) int lB[56 * 68];    // [pos][ch-dword 0..63], stride 68
    const int tid = threadIdx.x;
    const int P0 = blockIdx.x * 56;
    const int n = P0 / HWP;
    const int hw0 = P0 % HWP;
    const float* xb = x + (size_t)n * 256 * HWP + hw0;
#pragma unroll
    for (int k = 0; k < 14; ++k) {               // 3584 float4 chunks
        int e = tid + k * 256;
        int c = e / 14, pq = e % 14;
        float4v v = *(const float4v*)(xb + (size_t)c * HWP + pq * 4);
        int b0 = ((int)v[0] - 128) & 255;
        int b1 = ((int)v[1] - 128) & 255;
        int b2 = ((int)v[2] - 128) & 255;
        int b3 = ((int)v[3] - 128) & 255;
        lA[c * 15 + pq] = b0 | (b1 << 8) | (b2 << 16) | (b3 << 24);
    }
    __syncthreads();
#pragma unroll
    for (int k = 0; k < 4; ++k) {                // 896 4x4 byte-transpose units
        int u = tid + k * 256;
        if (u < 896) {
            int cg = u / 14, pq = u % 14;
            int d0 = lA[(cg * 4 + 0) * 15 + pq];
            int d1 = lA[(cg * 4 + 1) * 15 + pq];
            int d2 = lA[(cg * 4 + 2) * 15 + pq];
            int d3 = lA[(cg * 4 + 3) * 15 + pq];
#pragma unroll
            for (int j = 0; j < 4; ++j) {
                int sh = j * 8;
                int o = ((d0 >> sh) & 255) | (((d1 >> sh) & 255) << 8)
                      | (((d2 >> sh) & 255) << 16) | (((d3 >> sh) & 255) << 24);
                lB[(pq * 4 + j) * 68 + cg] = o;
            }
        }
    }
    __syncthreads();
#pragma unroll
    for (int k = 0; k < 4; ++k) {                // 896 16B output chunks
        int ch = tid + k * 256;
        if (ch < 896) {
            int g = ch / 224, rem = ch % 224;
            int pos = rem >> 2, c4 = rem & 3;
            int4v val = *(const int4v*)&lB[pos * 68 + g * 16 + c4 * 4];
            *(int4v*)(x8 + (size_t)g * PLN + (size_t)(P0 + pos) * 64 + c4 * 16) = val;
        }
    }
}

// ---------------- kernel 2: weights OIHW fp32 -> fragment-major int8 + per-oc sums --
// both weight tensors in one launch: blockIdx.x = which*256 + oc
__global__ __launch_bounds__(256) void k_w_prep(const float* __restrict__ wa,
                                                const float* __restrict__ wb,
                                                int8_t* __restrict__ w8a,
                                                int8_t* __restrict__ w8b,
                                                int* __restrict__ wsa,
                                                int* __restrict__ wsb) {
    __shared__ int red[256];
    const int which = blockIdx.x >> 8;
    const int oc = blockIdx.x & 255;
    const float* w = which ? wb : wa;
    int8_t* w8 = which ? w8b : w8a;
    int* wsum = which ? wsb : wsa;
    const int t = threadIdx.x;          // t = ic
    const float* src = w + (size_t)oc * 2304 + (size_t)t * 9;
    const int g = oc >> 5;
    const int l = ((t >> 4) & 1) * 32 + (oc & 31);
    const int j = t & 15;
    const int s2 = (t >> 5) & 1;
    const int kb = t >> 6;
    int acc = 0;
#pragma unroll
    for (int tap = 0; tap < 9; ++tap) {
        int wv = (int)src[tap];
        acc += wv;
        int oo = ((((tap * 4 + kb) * 2 + s2) * 8 + g) * 64 + l) * 16 + j;
        w8[oo] = (int8_t)wv;
    }
    red[t] = acc;
    __syncthreads();
    for (int st = 128; st > 0; st >>= 1) {
        if (t < st) red[t] += red[t + st];
        __syncthreads();
    }
    if (t == 0) wsum[oc] = red[0];
}

// ---------------- kernel 3: quantized 3x3 conv, 128pos x 128oc blocks ---------------
// Wave = 64 pos (mt=2) x 64 oc (nt=2).  A-slab (186 rows + pad row) staged once via
// global_load_lds (XOR-16 swizzle).  B prefetched TWO steps ahead (3-slot ring,
// 586-cyc lead > worst-case loaded L2 latency); A one step ahead.  Epilogues emit
// full-64B-line stores via LDS transpose (no partial-line HBM write amplification).
template<bool FUSED>
__global__ __launch_bounds__(256, 3) void k_qconv_t(const int8_t* __restrict__ in8,
        const int8_t* __restrict__ w8, const int* __restrict__ wsum,
        const float* __restrict__ s_in_p, const float* __restrict__ s_w_p,
        const float* __restrict__ s_out_p, const float* __restrict__ z_in_p,
        const float* __restrict__ z_out_p, int8_t* __restrict__ out8,
        const int8_t* __restrict__ x8, const float* __restrict__ sxp,
        const float* __restrict__ zxp, const float* __restrict__ sap,
        const float* __restrict__ zap, float* __restrict__ outf) {
    __shared__ __align__(16) int8_t slab[47872];   // 186 rows x 256 B + pad row
    const int tid = threadIdx.x;
    const int lane = tid & 63;
    const int half = lane >> 5;
    const int wv = tid >> 6;
    const int wq = wv >> 1;            // pos-half of block
    const int wo = wv & 1;             // oc-half of block
    const int p0 = blockIdx.x * 128;   // 392 position tiles
    const int gB = blockIdx.y * 128;   // 2 oc-blocks of 128

    // ---- stage A-slab: 2976 16B chunks; slot (q,cs) holds global chunk cs ^ (q&15)
#pragma unroll
    for (int k = 0; k < 12; ++k) {
        int chunkid = tid + k * 256;
        if (chunkid < 2976) {
            int q = chunkid >> 4;
            int cs = chunkid & 15;
            int cg = cs ^ (q & 15);
            int qg = p0 - 29 + q;
            qg = qg < 0 ? 0 : (qg > NPOS - 1 ? NPOS - 1 : qg);
            const int8_t* src = in8 + (size_t)(cg >> 2) * PLN
                                    + (size_t)qg * 64 + (cg & 3) * 16;
            __builtin_amdgcn_global_load_lds((as1_cv*)src,
                                             (as3_v*)&slab[chunkid * 16], 16, 0, 0);
        }
    }

    // pad row: z_in - 128 splat
    const int zi = (int)z_in_p[0] - 128;
    const int spl = (zi & 0xff) * 0x01010101;
    if (tid < 16) {
        int4v pv; pv[0] = spl; pv[1] = spl; pv[2] = spl; pv[3] = spl;
        *(int4v*)&slab[PAD_OFF + tid * 16] = pv;
    }

    // per-lane geometry + swizzled A base address per (tap, mt)
    int rowpos[2], ph[2], pw[2];
#pragma unroll
    for (int mt = 0; mt < 2; ++mt) {
        rowpos[mt] = wq * 64 + mt * 32 + (lane & 31);
        int p = p0 + rowpos[mt];
        int hw = p % HWP;
        ph[mt] = hw / 28;
        pw[mt] = hw % 28;
    }
    int abz[9][2];
#pragma unroll
    for (int tap = 0; tap < 9; ++tap) {
        const int dh = tap / 3 - 1;
        const int dw = tap % 3 - 1;
#pragma unroll
        for (int mt = 0; mt < 2; ++mt) {
            int q = rowpos[mt] + dh * 28 + dw + 29;          // 0..185
            bool ok = ((unsigned)(ph[mt] + dh) < 28u) & ((unsigned)(pw[mt] + dw) < 28u);
            int base = ok ? (q << 8) : PAD_OFF;              // pad row if out of image
            abz[tap][mt] = base ^ ((q & 15) << 4) ^ (half << 4);
        }
    }

    int16v acc[2][2];
#pragma unroll
    for (int mt = 0; mt < 2; ++mt)
#pragma unroll
        for (int nt = 0; nt < 2; ++nt)
#pragma unroll
            for (int r = 0; r < 16; ++r) acc[mt][nt][r] = 0;

    // B: wave's 64-oc slice; gg0 = oc-group base (32-wide groups)
    const int gg0 = blockIdx.y * 4 + wo * 2;
    const int8_t* wlane = w8 + gg0 * 1024 + lane * 16;

    int4v areg[2][2][2];   // [slot][mt][s]   (1-step prefetch)
    int4v breg[3][2][2];   // [slot][nt][s]   (2-step prefetch ring)

#define LOADB(u, slot)                                                      \
    {   const int8_t* wb_ = wlane + (size_t)(u) * 16384;                    \
        breg[slot][0][0] = *(const int4v*)(wb_);                            \
        breg[slot][1][0] = *(const int4v*)(wb_ + 1024);                     \
        breg[slot][0][1] = *(const int4v*)(wb_ + 8192);                     \
        breg[slot][1][1] = *(const int4v*)(wb_ + 9216); }
#define LOADA(u, slot)                                                      \
    {   const int tap_ = (u) >> 2, kb_ = (u) & 3;                           \
        areg[slot][0][0] = *(const int4v*)&slab[abz[tap_][0] ^ ((kb_*4+0)<<4)]; \
        areg[slot][0][1] = *(const int4v*)&slab[abz[tap_][0] ^ ((kb_*4+2)<<4)]; \
        areg[slot][1][0] = *(const int4v*)&slab[abz[tap_][1] ^ ((kb_*4+0)<<4)]; \
        areg[slot][1][1] = *(const int4v*)&slab[abz[tap_][1] ^ ((kb_*4+2)<<4)]; }

    LOADB(0, 0);           // B[0], B[1] before the barrier (independent of LDS)
    LOADB(1, 1);

    __syncthreads();       // the only barrier before the K-loop

    LOADA(0, 0);
#pragma unroll
    for (int u = 0; u < 36; ++u) {
        if (u < 34) LOADB(u + 2, (u + 2) % 3);   // 2-step (586-cyc) B lead
        if (u < 35) LOADA(u + 1, (u + 1) & 1);   // 1-step A lead (LDS, ~120 cyc)
        const int sl = u & 1;
        const int bs = u % 3;
#pragma unroll
        for (int s = 0; s < 2; ++s)
#pragma unroll
            for (int mt = 0; mt < 2; ++mt)
#pragma unroll
                for (int nt = 0; nt < 2; ++nt)
                    acc[mt][nt] = __builtin_amdgcn_mfma_i32_32x32x32_i8(
                        areg[sl][mt][s], breg[bs][nt][s], acc[mt][nt], 0, 0, 0);
    }
#undef LOADA
#undef LOADB

    // ---- epilogue: requant q = clip(rint(M*acc)+z_out, 0, 255) (exact integer path)
    const float Mf = s_in_p[0] * s_w_p[0] / s_out_p[0];
    const float zof = z_out_p[0];
    const int zoffi = 128 - (int)z_in_p[0];
    const int plane = blockIdx.y * 2 + wo;

    if (!FUSED) {
        // coalesced store path: bytes -> LDS tile (row stride 80) -> full 64B lines
        __syncthreads();                        // all waves done with slab A-data
        int8_t* tpb = slab + wv * 5120;         // 64 pos x 64 oc bytes, stride 80
#pragma unroll
        for (int mt = 0; mt < 2; ++mt)
#pragma unroll
            for (int nt = 0; nt < 2; ++nt) {
                int oc = gB + wo * 64 + nt * 32 + (lane & 31);
                int corr = zoffi * wsum[oc];
#pragma unroll
                for (int r = 0; r < 16; ++r) {
                    int prow = (r & 3) + 8 * (r >> 2) + 4 * half;   // 32x32 C/D layout
                    int pl = mt * 32 + prow;                        // local pos 0..63
                    float q = rintf(Mf * (float)(acc[mt][nt][r] + corr)) + zof;
                    q = fminf(fmaxf(q, 0.0f), 255.0f);
                    tpb[pl * 80 + nt * 32 + (lane & 31)] = (int8_t)((int)q - 128);
                }
            }
        // same-wave readback: lane <-> local pos; 4x dwordx4 = one full 64B line/lane
        int8_t* o8p = out8 + (size_t)plane * PLN + (size_t)(p0 + wq * 64 + lane) * 64;
        const int8_t* rowp = tpb + lane * 80;
#pragma unroll
        for (int k = 0; k < 4; ++k)
            *(int4v*)(o8p + k * 16) = *(const int4v*)(rowp + k * 16);
    } else {
        // fused residual qadd: out = clip(rint(ra*(qx-zx) + rb*(q2-z2)) + za, 0, 255)
        const float ra = sxp[0] / sap[0];
        const float rb = s_out_p[0] / sap[0];
        const float zx = zxp[0];
        const float z2 = z_out_p[0];
        const float za = zap[0];
        __syncthreads();                        // all waves done with slab A-data
        float* tp = (float*)slab + wv * 2080;   // 32 pos x 64 oc fp32, stride 65
        const int pl = lane & 31;
#pragma unroll
        for (int mt = 0; mt < 2; ++mt) {
#pragma unroll
            for (int nt = 0; nt < 2; ++nt) {
                int oc = gB + wo * 64 + nt * 32 + (lane & 31);
                int corr = zoffi * wsum[oc];
#pragma unroll
                for (int r = 0; r < 16; ++r) {
                    int prow = (r & 3) + 8 * (r >> 2) + 4 * half;
                    float q2 = rintf(Mf * (float)(acc[mt][nt][r] + corr)) + zof;
                    q2 = fminf(fmaxf(q2, 0.0f), 255.0f);
                    tp[prow * 65 + nt * 32 + (lane & 31)] = q2;
                }
            }
            // same-wave readback (DS in-order per wave; next mt overwrite is ordered)
            const int pglob = p0 + wq * 64 + mt * 32 + pl;
            const int n = pglob / HWP;
            const int hwo = pglob % HWP;
            const int8_t* x8p = x8 + (size_t)plane * PLN + (size_t)pglob * 64 + half * 32;
            int4v r0 = *(const int4v*)x8p;
            int4v r1 = *(const int4v*)(x8p + 16);
            int xb[8];
            xb[0] = r0[0]; xb[1] = r0[1]; xb[2] = r0[2]; xb[3] = r0[3];
            xb[4] = r1[0]; xb[5] = r1[1]; xb[6] = r1[2]; xb[7] = r1[3];
            float* obase = outf + ((size_t)(n * 256 + gB + wo * 64 + half * 32)) * HWP + hwo;
#pragma unroll
            for (int j = 0; j < 32; ++j) {
                int bv = (xb[j >> 2] >> ((j & 3) * 8)) & 255;
                int xval = (int)(int8_t)bv + 128;
                float q2 = tp[pl * 65 + half * 32 + j];
                float y = ra * ((float)xval - zx) + rb * (q2 - z2);
                float qf = rintf(y) + za;
                qf = fminf(fmaxf(qf, 0.0f), 255.0f);
                obase[(size_t)j * HWP] = qf;
            }
        }
    }
}

extern "C" void kernel_launch(void* const* d_in, const int* in_sizes, int n_in,
                              void* d_out, int out_size, void* d_ws, size_t ws_size,
                              hipStream_t stream) {
    (void)in_sizes; (void)n_in; (void)out_size; (void)ws_size;
    const float* x    = (const float*)d_in[0];
    const float* w1   = (const float*)d_in[1];
    const float* w2   = (const float*)d_in[2];
    const float* s_x  = (const float*)d_in[3];
    const float* z_x  = (const float*)d_in[4];
    const float* s_w1 = (const float*)d_in[5];
    const float* s_c1 = (const float*)d_in[6];
    const float* z_c1 = (const float*)d_in[7];
    const float* s_w2 = (const float*)d_in[8];
    const float* s_c2 = (const float*)d_in[9];
    const float* z_c2 = (const float*)d_in[10];
    const float* s_ad = (const float*)d_in[11];
    const float* z_ad = (const float*)d_in[12];
    float* out = (float*)d_out;

    // workspace layout (~26.9 MB)
    int8_t* ws    = (int8_t*)d_ws;
    int8_t* x8    = ws;                       // 4 planes x 3,211,264 = 12,845,056
    int8_t* o1    = ws + 12845056;            // 12,845,056 (conv1 out, plane-blocked)
    int8_t* w8a   = ws + 25690112;            // 589,824
    int8_t* w8b   = ws + 26279936;            // 589,824
    int*    wsum1 = (int*)(ws + 26869760);    // 1024
    int*    wsum2 = (int*)(ws + 26870784);    // 1024

    k_nhwc<<<896, 256, 0, stream>>>(x, x8);
    k_w_prep<<<512, 256, 0, stream>>>(w1, w2, w8a, w8b, wsum1, wsum2);
    k_qconv_t<false><<<dim3(392, 2), 256, 0, stream>>>(x8, w8a, wsum1,
        s_x, s_w1, s_c1, z_x, z_c1, o1,
        nullptr, nullptr, nullptr, nullptr, nullptr, nullptr);
    k_qconv_t<true><<<dim3(392, 2), 256, 0, stream>>>(o1, w8b, wsum2,
        s_c1, s_w2, s_c2, z_c1, z_c2, nullptr,
        x8, s_x, z_x, s_ad, z_ad, out);
}

// Round 9
// 210.044 us; speedup vs baseline: 1.0335x; 1.0133x over previous
//
#include <hip/hip_runtime.h>
#include <stdint.h>

#define HWP 784                // 28*28
#define NPOS 50176             // 64*784 flat positions
#define PLN ((size_t)NPOS * 64)  // plane stride bytes: [g][pos][64ch]
#define PAD_OFF 31232          // slab offset of the 256-B pad row (122*256)

typedef int   int4v   __attribute__((ext_vector_type(4)));
typedef int   int16v  __attribute__((ext_vector_type(16)));
typedef float float4v __attribute__((ext_vector_type(4)));
using as1_cv = const __attribute__((address_space(1))) void;
using as3_v  = __attribute__((address_space(3))) void;

// ---------------- kernel 1: x NCHW fp32 -> plane-blocked i8 (value-128) -------------
__global__ __launch_bounds__(256) void k_nhwc(const float* __restrict__ x,
                                              int8_t* __restrict__ x8) {
    __shared__ int lA[256 * 15];                 // [c][pq] pos-packed, stride 15
    __shared__ __align__(16) int lB[56 * 68];    // [pos][ch-dword 0..63], stride 68
    const int tid = threadIdx.x;
    const int P0 = blockIdx.x * 56;
    const int n = P0 / HWP;
    const int hw0 = P0 % HWP;
    const float* xb = x + (size_t)n * 256 * HWP + hw0;
#pragma unroll
    for (int k = 0; k < 14; ++k) {               // 3584 float4 chunks
        int e = tid + k * 256;
        int c = e / 14, pq = e % 14;
        float4v v = *(const float4v*)(xb + (size_t)c * HWP + pq * 4);
        int b0 = ((int)v[0] - 128) & 255;
        int b1 = ((int)v[1] - 128) & 255;
        int b2 = ((int)v[2] - 128) & 255;
        int b3 = ((int)v[3] - 128) & 255;
        lA[c * 15 + pq] = b0 | (b1 << 8) | (b2 << 16) | (b3 << 24);
    }
    __syncthreads();
#pragma unroll
    for (int k = 0; k < 4; ++k) {                // 896 4x4 byte-transpose units
        int u = tid + k * 256;
        if (u < 896) {
            int cg = u / 14, pq = u % 14;
            int d0 = lA[(cg * 4 + 0) * 15 + pq];
            int d1 = lA[(cg * 4 + 1) * 15 + pq];
            int d2 = lA[(cg * 4 + 2) * 15 + pq];
            int d3 = lA[(cg * 4 + 3) * 15 + pq];
#pragma unroll
            for (int j = 0; j < 4; ++j) {
                int sh = j * 8;
                int o = ((d0 >> sh) & 255) | (((d1 >> sh) & 255) << 8)
                      | (((d2 >> sh) & 255) << 16) | (((d3 >> sh) & 255) << 24);
                lB[(pq * 4 + j) * 68 + cg] = o;
            }
        }
    }
    __syncthreads();
#pragma unroll
    for (int k = 0; k < 4; ++k) {                // 896 16B output chunks
        int ch = tid + k * 256;
        if (ch < 896) {
            int g = ch / 224, rem = ch % 224;
            int pos = rem >> 2, c4 = rem & 3;
            int4v val = *(const int4v*)&lB[pos * 68 + g * 16 + c4 * 4];
            *(int4v*)(x8 + (size_t)g * PLN + (size_t)(P0 + pos) * 64 + c4 * 16) = val;
        }
    }
}

// ---------------- kernel 2: weights OIHW fp32 -> fragment-major int8 + per-oc sums --
// both weight tensors in one launch: blockIdx.x = which*256 + oc
__global__ __launch_bounds__(256) void k_w_prep(const float* __restrict__ wa,
                                                const float* __restrict__ wb,
                                                int8_t* __restrict__ w8a,
                                                int8_t* __restrict__ w8b,
                                                int* __restrict__ wsa,
                                                int* __restrict__ wsb) {
    __shared__ int red[256];
    const int which = blockIdx.x >> 8;
    const int oc = blockIdx.x & 255;
    const float* w = which ? wb : wa;
    int8_t* w8 = which ? w8b : w8a;
    int* wsum = which ? wsb : wsa;
    const int t = threadIdx.x;          // t = ic
    const float* src = w + (size_t)oc * 2304 + (size_t)t * 9;
    const int g = oc >> 5;
    const int l = ((t >> 4) & 1) * 32 + (oc & 31);
    const int j = t & 15;
    const int s2 = (t >> 5) & 1;
    const int kb = t >> 6;
    int acc = 0;
#pragma unroll
    for (int tap = 0; tap < 9; ++tap) {
        int wv = (int)src[tap];
        acc += wv;
        int oo = ((((tap * 4 + kb) * 2 + s2) * 8 + g) * 64 + l) * 16 + j;
        w8[oo] = (int8_t)wv;
    }
    red[t] = acc;
    __syncthreads();
    for (int st = 128; st > 0; st >>= 1) {
        if (t < st) red[t] += red[t + st];
        __syncthreads();
    }
    if (t == 0) wsum[oc] = red[0];
}

// ---------------- kernel 3: quantized 3x3 conv, 64pos x 256oc blocks ----------------
// ONE ROUND: grid 784 blocks, 4 blocks/CU resident (LDS 33.3 KB, VGPR capped by
// __launch_bounds__(256,4)) -> every block starts at t=0, zero tail rounds.
// Wave wv owns the full 64-pos tile x its 64-oc slice (mt=2, nt=2: 8 MFMA = 293
// SIMD-cyc per K-step; 4 waves/SIMD provide TLP).  A-slab (122 rows + pad row)
// staged once via global_load_lds (XOR-16 swizzle); compiler pipelines the fully
// unrolled 36-step K-loop within the register cap.  Epilogues store full 64-B lines.
template<bool FUSED>
__global__ __launch_bounds__(256, 4) void k_qconv_t(const int8_t* __restrict__ in8,
        const int8_t* __restrict__ w8, const int* __restrict__ wsum,
        const float* __restrict__ s_in_p, const float* __restrict__ s_w_p,
        const float* __restrict__ s_out_p, const float* __restrict__ z_in_p,
        const float* __restrict__ z_out_p, int8_t* __restrict__ out8,
        const int8_t* __restrict__ x8, const float* __restrict__ sxp,
        const float* __restrict__ zxp, const float* __restrict__ sap,
        const float* __restrict__ zap, float* __restrict__ outf) {
    __shared__ __align__(16) int8_t slab[33280];   // 122 rows x 256 B + pad row (+ep)
    const int tid = threadIdx.x;
    const int lane = tid & 63;
    const int half = lane >> 5;
    const int wv = tid >> 6;           // oc-slice 0..3 (also output plane)
    const int p0 = blockIdx.x * 64;    // 784 position tiles

    // ---- stage A-slab: 1952 16B chunks; slot (q,cs) holds global chunk cs ^ (q&15)
#pragma unroll
    for (int k = 0; k < 8; ++k) {
        int chunkid = tid + k * 256;
        if (chunkid < 1952) {
            int q = chunkid >> 4;
            int cs = chunkid & 15;
            int cg = cs ^ (q & 15);
            int qg = p0 - 29 + q;
            qg = qg < 0 ? 0 : (qg > NPOS - 1 ? NPOS - 1 : qg);
            const int8_t* src = in8 + (size_t)(cg >> 2) * PLN
                                    + (size_t)qg * 64 + (cg & 3) * 16;
            __builtin_amdgcn_global_load_lds((as1_cv*)src,
                                             (as3_v*)&slab[chunkid * 16], 16, 0, 0);
        }
    }

    // pad row: z_in - 128 splat
    const int zi = (int)z_in_p[0] - 128;
    const int spl = (zi & 0xff) * 0x01010101;
    if (tid < 16) {
        int4v pv; pv[0] = spl; pv[1] = spl; pv[2] = spl; pv[3] = spl;
        *(int4v*)&slab[PAD_OFF + tid * 16] = pv;
    }

    // per-lane geometry
    int rowpos[2], ph[2], pw[2];
#pragma unroll
    for (int mt = 0; mt < 2; ++mt) {
        rowpos[mt] = mt * 32 + (lane & 31);
        int p = p0 + rowpos[mt];
        int hw = p % HWP;
        ph[mt] = hw / 28;
        pw[mt] = hw % 28;
    }

    int16v acc[2][2];
#pragma unroll
    for (int mt = 0; mt < 2; ++mt)
#pragma unroll
        for (int nt = 0; nt < 2; ++nt)
#pragma unroll
            for (int r = 0; r < 16; ++r) acc[mt][nt][r] = 0;

    // B: wave's 64-oc slice (gg = wv*2 + nt)
    const int8_t* wlane = w8 + wv * 2048 + lane * 16;

    __syncthreads();       // the only barrier before the K-loop

#pragma unroll
    for (int u = 0; u < 36; ++u) {
        const int tap = u >> 2, kb = u & 3;
        const int dh = tap / 3 - 1;
        const int dw = tap % 3 - 1;
        const int8_t* wb_ = wlane + (size_t)u * 16384;
        int4v b[2][2];                               // [nt][s]
        b[0][0] = *(const int4v*)(wb_);
        b[1][0] = *(const int4v*)(wb_ + 1024);
        b[0][1] = *(const int4v*)(wb_ + 8192);
        b[1][1] = *(const int4v*)(wb_ + 9216);
        int4v a[2][2];                               // [mt][s]
#pragma unroll
        for (int mt = 0; mt < 2; ++mt) {
            int q = rowpos[mt] + dh * 28 + dw + 29;  // 0..121
            bool ok = ((unsigned)(ph[mt] + dh) < 28u) & ((unsigned)(pw[mt] + dw) < 28u);
            int ab = (ok ? (q << 8) : PAD_OFF) ^ ((q & 15) << 4) ^ (half << 4);
            a[mt][0] = *(const int4v*)&slab[ab ^ ((kb * 4 + 0) << 4)];
            a[mt][1] = *(const int4v*)&slab[ab ^ ((kb * 4 + 2) << 4)];
        }
#pragma unroll
        for (int s = 0; s < 2; ++s)
#pragma unroll
            for (int mt = 0; mt < 2; ++mt)
#pragma unroll
                for (int nt = 0; nt < 2; ++nt)
                    acc[mt][nt] = __builtin_amdgcn_mfma_i32_32x32x32_i8(
                        a[mt][s], b[nt][s], acc[mt][nt], 0, 0, 0);
    }

    // ---- epilogue: requant q = clip(rint(M*acc)+z_out, 0, 255) (exact integer path)
    const float Mf = s_in_p[0] * s_w_p[0] / s_out_p[0];
    const float zof = z_out_p[0];
    const int zoffi = 128 - (int)z_in_p[0];

    if (!FUSED) {
        // coalesced store path: bytes -> LDS tile (row stride 80) -> full 64B lines
        __syncthreads();                        // all waves done with slab A-data
        int8_t* tpb = slab + wv * 5120;         // 64 pos x 64 oc bytes, stride 80
#pragma unroll
        for (int mt = 0; mt < 2; ++mt)
#pragma unroll
            for (int nt = 0; nt < 2; ++nt) {
                int oc = wv * 64 + nt * 32 + (lane & 31);
                int corr = zoffi * wsum[oc];
#pragma unroll
                for (int r = 0; r < 16; ++r) {
                    int prow = (r & 3) + 8 * (r >> 2) + 4 * half;   // 32x32 C/D layout
                    int pl = mt * 32 + prow;                        // local pos 0..63
                    float q = rintf(Mf * (float)(acc[mt][nt][r] + corr)) + zof;
                    q = fminf(fmaxf(q, 0.0f), 255.0f);
                    tpb[pl * 80 + nt * 32 + (lane & 31)] = (int8_t)((int)q - 128);
                }
            }
        // same-wave readback: lane <-> local pos; 4x dwordx4 = one full 64B line/lane
        int8_t* o8p = out8 + (size_t)wv * PLN + (size_t)(p0 + lane) * 64;
        const int8_t* rowp = tpb + lane * 80;
#pragma unroll
        for (int k = 0; k < 4; ++k)
            *(int4v*)(o8p + k * 16) = *(const int4v*)(rowp + k * 16);
    } else {
        // fused residual qadd: out = clip(rint(ra*(qx-zx) + rb*(q2-z2)) + za, 0, 255)
        const float ra = sxp[0] / sap[0];
        const float rb = s_out_p[0] / sap[0];
        const float zx = zxp[0];
        const float z2 = z_out_p[0];
        const float za = zap[0];
        __syncthreads();                        // all waves done with slab A-data
        float* tp = (float*)slab + wv * 2080;   // 32 pos x 64 oc fp32, stride 65
        const int pl = lane & 31;
#pragma unroll
        for (int mt = 0; mt < 2; ++mt) {
#pragma unroll
            for (int nt = 0; nt < 2; ++nt) {
                int oc = wv * 64 + nt * 32 + (lane & 31);
                int corr = zoffi * wsum[oc];
#pragma unroll
                for (int r = 0; r < 16; ++r) {
                    int prow = (r & 3) + 8 * (r >> 2) + 4 * half;
                    float q2 = rintf(Mf * (float)(acc[mt][nt][r] + corr)) + zof;
                    q2 = fminf(fmaxf(q2, 0.0f), 255.0f);
                    tp[prow * 65 + nt * 32 + (lane & 31)] = q2;
                }
            }
            // same-wave readback (DS in-order per wave; next mt overwrite is ordered)
            const int pglob = p0 + mt * 32 + pl;
            const int n = pglob / HWP;
            const int hwo = pglob % HWP;
            const int8_t* x8p = x8 + (size_t)wv * PLN + (size_t)pglob * 64 + half * 32;
            int4v r0 = *(const int4v*)x8p;
            int4v r1 = *(const int4v*)(x8p + 16);
            int xb[8];
            xb[0] = r0[0]; xb[1] = r0[1]; xb[2] = r0[2]; xb[3] = r0[3];
            xb[4] = r1[0]; xb[5] = r1[1]; xb[6] = r1[2]; xb[7] = r1[3];
            float* obase = outf + ((size_t)(n * 256 + wv * 64 + half * 32)) * HWP + hwo;
#pragma unroll
            for (int j = 0; j < 32; ++j) {
                int bv = (xb[j >> 2] >> ((j & 3) * 8)) & 255;
                int xval = (int)(int8_t)bv + 128;
                float q2 = tp[pl * 65 + half * 32 + j];
                float y = ra * ((float)xval - zx) + rb * (q2 - z2);
                float qf = rintf(y) + za;
                qf = fminf(fmaxf(qf, 0.0f), 255.0f);
                obase[(size_t)j * HWP] = qf;
            }
        }
    }
}

extern "C" void kernel_launch(void* const* d_in, const int* in_sizes, int n_in,
                              void* d_out, int out_size, void* d_ws, size_t ws_size,
                              hipStream_t stream) {
    (void)in_sizes; (void)n_in; (void)out_size; (void)ws_size;
    const float* x    = (const float*)d_in[0];
    const float* w1   = (const float*)d_in[1];
    const float* w2   = (const float*)d_in[2];
    const float* s_x  = (const float*)d_in[3];
    const float* z_x  = (const float*)d_in[4];
    const float* s_w1 = (const float*)d_in[5];
    const float* s_c1 = (const float*)d_in[6];
    const float* z_c1 = (const float*)d_in[7];
    const float* s_w2 = (const float*)d_in[8];
    const float* s_c2 = (const float*)d_in[9];
    const float* z_c2 = (const float*)d_in[10];
    const float* s_ad = (const float*)d_in[11];
    const float* z_ad = (const float*)d_in[12];
    float* out = (float*)d_out;

    // workspace layout (~26.9 MB)
    int8_t* ws    = (int8_t*)d_ws;
    int8_t* x8    = ws;                       // 4 planes x 3,211,264 = 12,845,056
    int8_t* o1    = ws + 12845056;            // 12,845,056 (conv1 out, plane-blocked)
    int8_t* w8a   = ws + 25690112;            // 589,824
    int8_t* w8b   = ws + 26279936;            // 589,824
    int*    wsum1 = (int*)(ws + 26869760);    // 1024
    int*    wsum2 = (int*)(ws + 26870784);    // 1024

    k_nhwc<<<896, 256, 0, stream>>>(x, x8);
    k_w_prep<<<512, 256, 0, stream>>>(w1, w2, w8a, w8b, wsum1, wsum2);
    k_qconv_t<false><<<784, 256, 0, stream>>>(x8, w8a, wsum1,
        s_x, s_w1, s_c1, z_x, z_c1, o1,
        nullptr, nullptr, nullptr, nullptr, nullptr, nullptr);
    k_qconv_t<true><<<784, 256, 0, stream>>>(o1, w8b, wsum2,
        s_c1, s_w2, s_c2, z_c1, z_c2, nullptr,
        x8, s_x, z_x, s_ad, z_ad, out);
}